// Round 7
// baseline (191.055 us; speedup 1.0000x reference)
//
#include <hip/hip_runtime.h>

typedef _Float16 f16;
typedef f16 f16x2 __attribute__((ext_vector_type(2)));
typedef f16 f16x4 __attribute__((ext_vector_type(4)));
typedef f16 f16x8 __attribute__((ext_vector_type(8)));
typedef float f32x4 __attribute__((ext_vector_type(4)));
typedef int int4a __attribute__((ext_vector_type(4), aligned(4)));  // align-4 dwordx4 load

#define BSH 7    // 128 nodes per bucket
#define BN 128
#define CHUNK 8192  // edges per hist/place block
#define LCAP 4096   // LDS edge cap per bucket (mean ~2046, +45 sigma)
#define NBMAX 512
#define PMAX 512    // padded partial count (nb2 <= 512)

// ============ K0: bucket-hist (blocks 0..nblk-1) + W1/W2 f16 transpose (2 extra blocks) ============
__global__ __launch_bounds__(256) void degh(const int* __restrict__ dst, int* __restrict__ histG,
                                            const float* __restrict__ W1,
                                            const float* __restrict__ W2, f16* __restrict__ w1t,
                                            f16* __restrict__ w2t, int E, int NB, int nblk) {
    const int t = threadIdx.x, blk = blockIdx.x;
    if (blk < nblk) {  // ---- hist role ----
        __shared__ int hist[NBMAX];
        for (int i = t; i < NB; i += 256) hist[i] = 0;
        __syncthreads();
        int lo = blk * CHUNK, hi = min(lo + CHUNK, E);
        for (int i = lo + t; i < hi; i += 256) atomicAdd(&hist[dst[i] >> BSH], 1);
        __syncthreads();
        for (int i = t; i < NB; i += 256) histG[(size_t)i * nblk + blk] = hist[i];
        return;
    }
    if (blk == nblk) {  // ---- W1^T -> f16 : w1t[n][k] = W1[k][n] ----
        for (int idx = t; idx < 128 * 128; idx += 256) {
            int n = idx >> 7, k = idx & 127;
            w1t[idx] = (f16)W1[k * 128 + n];
        }
        return;
    }
    // ---- W2^T -> f16 : w2t[n][k] = W2[k][n], n<64, k<128 ----
    for (int idx = t; idx < 64 * 128; idx += 256) {
        int n = idx >> 7, k = idx & 127;
        w2t[idx] = (f16)W2[k * 64 + n];
    }
}

// ============ K2: per-256-chunk exclusive scan (in place), partials to bsum ============
__global__ __launch_bounds__(256) void scanA(int* __restrict__ a, int* __restrict__ bsum, int L) {
    __shared__ int tmp[256];
    int tid = threadIdx.x;
    int i = blockIdx.x * 256 + tid;
    int v = (i < L) ? a[i] : 0;
    tmp[tid] = v;
    __syncthreads();
    for (int o = 1; o < 256; o <<= 1) {
        int t2 = (tid >= o) ? tmp[tid - o] : 0;
        __syncthreads();
        tmp[tid] += t2;
        __syncthreads();
    }
    if (i < L) a[i] = tmp[tid] - v;  // exclusive within chunk
    if (tid == 255) bsum[blockIdx.x] = tmp[255];
}

// ---- device helper: exclusive-scan bsum[nb2] into LDS excl[PMAX] (256-thread block) ----
__device__ __forceinline__ void scan_partials(const int* __restrict__ bsum, int nb2,
                                              int* excl /*PMAX*/, int* work /*PMAX*/) {
    const int t = threadIdx.x & 255;
    for (int i = t; i < PMAX; i += 256) work[i] = (i < nb2) ? bsum[i] : 0;
    __syncthreads();
    for (int o = 1; o < PMAX; o <<= 1) {
        for (int i = t; i < PMAX; i += 256) excl[i] = work[i] + ((i >= o) ? work[i - o] : 0);
        __syncthreads();
        for (int i = t; i < PMAX; i += 256) work[i] = excl[i];
        __syncthreads();
    }
    for (int i = t; i < PMAX; i += 256) excl[i] = (i == 0) ? 0 : work[i - 1];
    __syncthreads();
}

// ============ K3: place edges bucket-contiguously (scan_partials inlined) ============
__global__ __launch_bounds__(256) void placeK(const int* __restrict__ src,
                                              const int* __restrict__ dst,
                                              const int* __restrict__ histG,
                                              const int* __restrict__ bsum, int nb2,
                                              int* __restrict__ sorted, int E, int NB, int nblk) {
    __shared__ int excl[PMAX];
    __shared__ int work[PMAX];
    __shared__ int ofs[NBMAX];
    const int t = threadIdx.x, blk = blockIdx.x;
    scan_partials(bsum, nb2, excl, work);
    for (int i = t; i < NB; i += 256) {
        int idx = i * nblk + blk;
        ofs[i] = histG[idx] + excl[idx >> 8];
    }
    __syncthreads();
    int lo = blk * CHUNK, hi = min(lo + CHUNK, E);
    for (int i = lo + t; i < hi; i += 256) {
        int d = dst[i];
        int pos = atomicAdd(&ofs[d >> BSH], 1);
        sorted[pos] = (src[i] << BSH) | (d & (BN - 1));
    }
}

// ============ K4: bucket node-sort (blocks 0..NB-1) || MFMA GEMM1 (remaining blocks) ============
__global__ __launch_bounds__(256) void k4(const int* __restrict__ histG,
                                          const int* __restrict__ bsum, int nb2,
                                          const int* __restrict__ sorted,
                                          int* __restrict__ rowstart, float* __restrict__ dinv,
                                          int* __restrict__ csr_src, const float* __restrict__ x,
                                          const f16* __restrict__ w1t, f16* __restrict__ h,
                                          int N, int E, int NB, int nblk) {
    __shared__ union SM {
        struct {
            f16 aT[64 * 136];
            f16 bT[128 * 136];
        } g;
        struct {
            int ent[LCAP];
            int hist[BN];
            int lofs[BN];
            int excl[PMAX];
            int work[PMAX];
        } b;
    } sm;
    const int t = threadIdx.x;

    if ((int)blockIdx.x < NB) {  // ---- bucket_build role ----
        const int b = blockIdx.x;
        scan_partials(bsum, nb2, sm.b.excl, sm.b.work);
        const int i0 = b * nblk;
        const int base = histG[i0] + sm.b.excl[i0 >> 8];
        const int endb = (b == NB - 1) ? E : (histG[i0 + nblk] + sm.b.excl[(i0 + nblk) >> 8]);
        int total = min(endb - base, LCAP);
        if (b == 0 && t == 0) rowstart[N] = E;

        for (int i = t; i < total; i += 256) sm.b.ent[i] = sorted[base + i];
        if (t < BN) sm.b.hist[t] = 0;
        __syncthreads();
        for (int i = t; i < total; i += 256) atomicAdd(&sm.b.hist[sm.b.ent[i] & (BN - 1)], 1);
        __syncthreads();
        if (t < BN) sm.b.lofs[t] = sm.b.hist[t];
        __syncthreads();
        for (int o = 1; o < BN; o <<= 1) {
            int v = (t < BN && t >= o) ? sm.b.lofs[t - o] : 0;
            __syncthreads();
            if (t < BN) sm.b.lofs[t] += v;
            __syncthreads();
        }
        if (t < BN) {
            int ex = sm.b.lofs[t] - sm.b.hist[t];
            int node = (b << BSH) + t;
            if (node < N) {
                rowstart[node] = base + ex;
                dinv[node] = rsqrtf((float)sm.b.hist[t] + 1.0f);  // +1 self-loop
            }
            sm.b.lofs[t] = ex;
        }
        __syncthreads();
        for (int i = t; i < total; i += 256) {
            int e = sm.b.ent[i];
            int pos = atomicAdd(&sm.b.lofs[e & (BN - 1)], 1);
            csr_src[base + pos] = e >> BSH;
        }
        return;
    }

    // ---- gemm1 role: h[64 x 128] = x_tile @ W1 (f16) ----
    const int gb = blockIdx.x - NB;
    const int row0 = gb * 64;
    {  // stage A (fp32 -> fp16), k-contiguous
        int r = t >> 2, s = (t & 3) * 32;
        bool ok = (row0 + r) < N;
        const float* xp = x + (size_t)(row0 + r) * 128 + s;
        f16* dp = &sm.g.aT[r * 136 + s];
#pragma unroll
        for (int c = 0; c < 4; ++c) {
            f16x8 hv;
            if (ok) {
                float4 f0 = *(const float4*)(xp + c * 8);
                float4 f1 = *(const float4*)(xp + c * 8 + 4);
                hv[0] = (f16)f0.x; hv[1] = (f16)f0.y; hv[2] = (f16)f0.z; hv[3] = (f16)f0.w;
                hv[4] = (f16)f1.x; hv[5] = (f16)f1.y; hv[6] = (f16)f1.z; hv[7] = (f16)f1.w;
            } else {
#pragma unroll
                for (int j = 0; j < 8; ++j) hv[j] = (f16)0.f;
            }
            *(f16x8*)(dp + c * 8) = hv;
        }
    }
    for (int idx = t; idx < 128 * 16; idx += 256) {  // stage W1^T (pre-converted, vectorized)
        int n = idx >> 4, c = idx & 15;
        *(f16x8*)&sm.g.bT[n * 136 + c * 8] = *(const f16x8*)&w1t[n * 128 + c * 8];
    }
    __syncthreads();

    const int w = t >> 6, lane = t & 63, m15 = lane & 15, quad = lane >> 4;
    f32x4 acc[8];
#pragma unroll
    for (int c = 0; c < 8; ++c) acc[c] = (f32x4){0.f, 0.f, 0.f, 0.f};
    const f16* ar = &sm.g.aT[(w * 16 + m15) * 136 + quad * 8];
#pragma unroll
    for (int k0 = 0; k0 < 128; k0 += 32) {
        f16x8 a = *(const f16x8*)(ar + k0);
#pragma unroll
        for (int c = 0; c < 8; ++c) {
            f16x8 b = *(const f16x8*)(&sm.g.bT[(c * 16 + m15) * 136 + k0 + quad * 8]);
            acc[c] = __builtin_amdgcn_mfma_f32_16x16x32_f16(a, b, acc[c], 0, 0, 0);
        }
    }
#pragma unroll
    for (int c = 0; c < 8; ++c)
#pragma unroll
        for (int r = 0; r < 4; ++r) {
            int row = row0 + w * 16 + quad * 4 + r;
            if (row < N) h[(size_t)row * 128 + c * 16 + m15] = (f16)acc[c][r];
        }
}

// ============ K5: gather1, 2 nodes/wave (32 lanes/node, f16x4), 8-edge unroll ============
__global__ __launch_bounds__(256) void gather1(const int* __restrict__ rowstart,
                                               const int* __restrict__ csr_src,
                                               const float* __restrict__ dinv,
                                               const f16* __restrict__ h,
                                               const float* __restrict__ b1,
                                               f16* __restrict__ r1, int N) {
    int wid = (blockIdx.x * 256 + threadIdx.x) >> 6;
    int lane = threadIdx.x & 63;
    int sub = lane >> 5, l32 = lane & 31;
    int node = wid * 2 + sub;
    if (node >= N) return;
    int beg = rowstart[node], end = rowstart[node + 1];
    float dn = dinv[node];
    const f16x4* hv = (const f16x4*)h;  // 32 f16x4 per 128-feat row

    f16x4 sv = hv[(size_t)node * 32 + l32];  // self term
    float a0 = dn * (float)sv[0], a1 = dn * (float)sv[1];
    float a2 = dn * (float)sv[2], a3 = dn * (float)sv[3];
    int i = beg;
    for (; i + 8 <= end; i += 8) {
        int4a sA = *(const int4a*)(csr_src + i);
        int4a sB = *(const int4a*)(csr_src + i + 4);
        float w0 = dinv[sA.x], w1 = dinv[sA.y], w2 = dinv[sA.z], w3 = dinv[sA.w];
        float w4 = dinv[sB.x], w5 = dinv[sB.y], w6 = dinv[sB.z], w7 = dinv[sB.w];
        f16x4 v0 = hv[(size_t)sA.x * 32 + l32];
        f16x4 v1 = hv[(size_t)sA.y * 32 + l32];
        f16x4 v2 = hv[(size_t)sA.z * 32 + l32];
        f16x4 v3 = hv[(size_t)sA.w * 32 + l32];
        f16x4 v4 = hv[(size_t)sB.x * 32 + l32];
        f16x4 v5 = hv[(size_t)sB.y * 32 + l32];
        f16x4 v6 = hv[(size_t)sB.z * 32 + l32];
        f16x4 v7 = hv[(size_t)sB.w * 32 + l32];
        a0 = fmaf(w0, (float)v0[0], a0); a1 = fmaf(w0, (float)v0[1], a1);
        a2 = fmaf(w0, (float)v0[2], a2); a3 = fmaf(w0, (float)v0[3], a3);
        a0 = fmaf(w1, (float)v1[0], a0); a1 = fmaf(w1, (float)v1[1], a1);
        a2 = fmaf(w1, (float)v1[2], a2); a3 = fmaf(w1, (float)v1[3], a3);
        a0 = fmaf(w2, (float)v2[0], a0); a1 = fmaf(w2, (float)v2[1], a1);
        a2 = fmaf(w2, (float)v2[2], a2); a3 = fmaf(w2, (float)v2[3], a3);
        a0 = fmaf(w3, (float)v3[0], a0); a1 = fmaf(w3, (float)v3[1], a1);
        a2 = fmaf(w3, (float)v3[2], a2); a3 = fmaf(w3, (float)v3[3], a3);
        a0 = fmaf(w4, (float)v4[0], a0); a1 = fmaf(w4, (float)v4[1], a1);
        a2 = fmaf(w4, (float)v4[2], a2); a3 = fmaf(w4, (float)v4[3], a3);
        a0 = fmaf(w5, (float)v5[0], a0); a1 = fmaf(w5, (float)v5[1], a1);
        a2 = fmaf(w5, (float)v5[2], a2); a3 = fmaf(w5, (float)v5[3], a3);
        a0 = fmaf(w6, (float)v6[0], a0); a1 = fmaf(w6, (float)v6[1], a1);
        a2 = fmaf(w6, (float)v6[2], a2); a3 = fmaf(w6, (float)v6[3], a3);
        a0 = fmaf(w7, (float)v7[0], a0); a1 = fmaf(w7, (float)v7[1], a1);
        a2 = fmaf(w7, (float)v7[2], a2); a3 = fmaf(w7, (float)v7[3], a3);
    }
    if (i + 4 <= end) {
        int4a s4 = *(const int4a*)(csr_src + i);
        float w0 = dinv[s4.x], w1 = dinv[s4.y], w2 = dinv[s4.z], w3 = dinv[s4.w];
        f16x4 v0 = hv[(size_t)s4.x * 32 + l32];
        f16x4 v1 = hv[(size_t)s4.y * 32 + l32];
        f16x4 v2 = hv[(size_t)s4.z * 32 + l32];
        f16x4 v3 = hv[(size_t)s4.w * 32 + l32];
        a0 = fmaf(w0, (float)v0[0], a0); a1 = fmaf(w0, (float)v0[1], a1);
        a2 = fmaf(w0, (float)v0[2], a2); a3 = fmaf(w0, (float)v0[3], a3);
        a0 = fmaf(w1, (float)v1[0], a0); a1 = fmaf(w1, (float)v1[1], a1);
        a2 = fmaf(w1, (float)v1[2], a2); a3 = fmaf(w1, (float)v1[3], a3);
        a0 = fmaf(w2, (float)v2[0], a0); a1 = fmaf(w2, (float)v2[1], a1);
        a2 = fmaf(w2, (float)v2[2], a2); a3 = fmaf(w2, (float)v2[3], a3);
        a0 = fmaf(w3, (float)v3[0], a0); a1 = fmaf(w3, (float)v3[1], a1);
        a2 = fmaf(w3, (float)v3[2], a2); a3 = fmaf(w3, (float)v3[3], a3);
        i += 4;
    }
    for (; i < end; ++i) {
        int s = csr_src[i];
        float w = dinv[s];
        f16x4 v = hv[(size_t)s * 32 + l32];
        a0 = fmaf(w, (float)v[0], a0); a1 = fmaf(w, (float)v[1], a1);
        a2 = fmaf(w, (float)v[2], a2); a3 = fmaf(w, (float)v[3], a3);
    }
    float4 bb = ((const float4*)b1)[l32];
    // r1~ = dinv[node] * relu(dinv[node]*sum + b1)  (pre-scaled for layer 2)
    float o0 = dn * fmaxf(fmaf(dn, a0, bb.x), 0.f);
    float o1 = dn * fmaxf(fmaf(dn, a1, bb.y), 0.f);
    float o2 = dn * fmaxf(fmaf(dn, a2, bb.z), 0.f);
    float o3 = dn * fmaxf(fmaf(dn, a3, bb.w), 0.f);
    ((f16x4*)r1)[(size_t)node * 32 + l32] = (f16x4){(f16)o0, (f16)o1, (f16)o2, (f16)o3};
}

// ============ K6: MFMA GEMM2: h2~[N x 64] = r1~ @ W2 (inputs pre-scaled) ============
__global__ __launch_bounds__(256) void gemm2(const f16* __restrict__ r1,
                                             const f16* __restrict__ w2t, f16* __restrict__ h2,
                                             int N) {
    __shared__ f16 aT[64 * 136];
    __shared__ f16 bT[64 * 136];  // W2^T [n][k]
    const int t = threadIdx.x;
    const int row0 = blockIdx.x * 64;
    {
        int r = t >> 2, s = (t & 3) * 32;
        bool ok = (row0 + r) < N;
        const f16* rp = r1 + (size_t)(row0 + r) * 128 + s;
        f16* dp = &aT[r * 136 + s];
#pragma unroll
        for (int c = 0; c < 4; ++c) {
            f16x8 hv;
            if (ok) hv = *(const f16x8*)(rp + c * 8);
            else {
#pragma unroll
                for (int j = 0; j < 8; ++j) hv[j] = (f16)0.f;
            }
            *(f16x8*)(dp + c * 8) = hv;
        }
    }
    for (int idx = t; idx < 64 * 16; idx += 256) {  // stage W2^T (pre-converted, vectorized)
        int n = idx >> 4, c = idx & 15;
        *(f16x8*)&bT[n * 136 + c * 8] = *(const f16x8*)&w2t[n * 128 + c * 8];
    }
    __syncthreads();

    const int w = t >> 6, lane = t & 63, m15 = lane & 15, quad = lane >> 4;
    f32x4 acc[4];
#pragma unroll
    for (int c = 0; c < 4; ++c) acc[c] = (f32x4){0.f, 0.f, 0.f, 0.f};
    const f16* ar = &aT[(w * 16 + m15) * 136 + quad * 8];
#pragma unroll
    for (int k0 = 0; k0 < 128; k0 += 32) {
        f16x8 a = *(const f16x8*)(ar + k0);
#pragma unroll
        for (int c = 0; c < 4; ++c) {
            f16x8 b = *(const f16x8*)(&bT[(c * 16 + m15) * 136 + k0 + quad * 8]);
            acc[c] = __builtin_amdgcn_mfma_f32_16x16x32_f16(a, b, acc[c], 0, 0, 0);
        }
    }
#pragma unroll
    for (int c = 0; c < 4; ++c)
#pragma unroll
        for (int r = 0; r < 4; ++r) {
            int row = row0 + w * 16 + quad * 4 + r;
            if (row < N) h2[(size_t)row * 64 + c * 16 + m15] = (f16)acc[c][r];
        }
}

// ============ K7: gather2, 4 nodes/wave (16 lanes/node, f16x4), 8-edge unroll ============
__global__ __launch_bounds__(256) void gather2(const int* __restrict__ rowstart,
                                               const int* __restrict__ csr_src,
                                               const float* __restrict__ dinv,
                                               const f16* __restrict__ h2,
                                               const float* __restrict__ b2,
                                               float* __restrict__ out, int N) {
    int wid = (blockIdx.x * 256 + threadIdx.x) >> 6;
    int lane = threadIdx.x & 63;
    int q = lane >> 4, l16 = lane & 15;
    int node = wid * 4 + q;
    if (node >= N) return;
    int beg = rowstart[node], end = rowstart[node + 1];
    float dn = dinv[node];
    const f16x4* h2v = (const f16x4*)h2;  // 16 f16x4 per 64-feat row

    f16x4 sv = h2v[(size_t)node * 16 + l16];  // self (pre-scaled)
    float a0 = (float)sv[0], a1 = (float)sv[1], a2 = (float)sv[2], a3 = (float)sv[3];
    int i = beg;
    for (; i + 8 <= end; i += 8) {
        int4a sA = *(const int4a*)(csr_src + i);
        int4a sB = *(const int4a*)(csr_src + i + 4);
        f16x4 v0 = h2v[(size_t)sA.x * 16 + l16];
        f16x4 v1 = h2v[(size_t)sA.y * 16 + l16];
        f16x4 v2 = h2v[(size_t)sA.z * 16 + l16];
        f16x4 v3 = h2v[(size_t)sA.w * 16 + l16];
        f16x4 v4 = h2v[(size_t)sB.x * 16 + l16];
        f16x4 v5 = h2v[(size_t)sB.y * 16 + l16];
        f16x4 v6 = h2v[(size_t)sB.z * 16 + l16];
        f16x4 v7 = h2v[(size_t)sB.w * 16 + l16];
        a0 += (float)v0[0]; a1 += (float)v0[1]; a2 += (float)v0[2]; a3 += (float)v0[3];
        a0 += (float)v1[0]; a1 += (float)v1[1]; a2 += (float)v1[2]; a3 += (float)v1[3];
        a0 += (float)v2[0]; a1 += (float)v2[1]; a2 += (float)v2[2]; a3 += (float)v2[3];
        a0 += (float)v3[0]; a1 += (float)v3[1]; a2 += (float)v3[2]; a3 += (float)v3[3];
        a0 += (float)v4[0]; a1 += (float)v4[1]; a2 += (float)v4[2]; a3 += (float)v4[3];
        a0 += (float)v5[0]; a1 += (float)v5[1]; a2 += (float)v5[2]; a3 += (float)v5[3];
        a0 += (float)v6[0]; a1 += (float)v6[1]; a2 += (float)v6[2]; a3 += (float)v6[3];
        a0 += (float)v7[0]; a1 += (float)v7[1]; a2 += (float)v7[2]; a3 += (float)v7[3];
    }
    if (i + 4 <= end) {
        int4a s4 = *(const int4a*)(csr_src + i);
        f16x4 v0 = h2v[(size_t)s4.x * 16 + l16];
        f16x4 v1 = h2v[(size_t)s4.y * 16 + l16];
        f16x4 v2 = h2v[(size_t)s4.z * 16 + l16];
        f16x4 v3 = h2v[(size_t)s4.w * 16 + l16];
        a0 += (float)v0[0]; a1 += (float)v0[1]; a2 += (float)v0[2]; a3 += (float)v0[3];
        a0 += (float)v1[0]; a1 += (float)v1[1]; a2 += (float)v1[2]; a3 += (float)v1[3];
        a0 += (float)v2[0]; a1 += (float)v2[1]; a2 += (float)v2[2]; a3 += (float)v2[3];
        a0 += (float)v3[0]; a1 += (float)v3[1]; a2 += (float)v3[2]; a3 += (float)v3[3];
        i += 4;
    }
    for (; i < end; ++i) {
        int s = csr_src[i];
        f16x4 v = h2v[(size_t)s * 16 + l16];
        a0 += (float)v[0]; a1 += (float)v[1]; a2 += (float)v[2]; a3 += (float)v[3];
    }
    float4 bb = ((const float4*)b2)[l16];
    float4 o;
    o.x = fmaf(dn, a0, bb.x);
    o.y = fmaf(dn, a1, bb.y);
    o.z = fmaf(dn, a2, bb.z);
    o.w = fmaf(dn, a3, bb.w);
    ((float4*)out)[(size_t)node * 16 + l16] = o;
}

extern "C" void kernel_launch(void* const* d_in, const int* in_sizes, int n_in,
                              void* d_out, int out_size, void* d_ws, size_t ws_size,
                              hipStream_t stream) {
    const float* x  = (const float*)d_in[0];
    const int*   ei = (const int*)d_in[1];
    const float* W1 = (const float*)d_in[2];
    const float* b1 = (const float*)d_in[3];
    const float* W2 = (const float*)d_in[4];
    const float* b2 = (const float*)d_in[5];

    const int N = in_sizes[0] / 128;  // 50000
    const int E = in_sizes[1] / 2;    // 800000
    const int* src = ei;
    const int* dst = ei + E;
    const int NB   = (N + BN - 1) >> BSH;      // 391
    const int nblk = (E + CHUNK - 1) / CHUNK;  // 98
    const int L    = NB * nblk;                // 38,318
    const int nb2  = (L + 255) / 256;          // 150 <= PMAX

    char* p = (char*)d_ws;
    auto bump = [&](size_t bytes) {
        char* r = p;
        p += (bytes + 255) & ~(size_t)255;
        return r;
    };
    int*   histG    = (int*)bump((size_t)L * 4);
    int*   bsum     = (int*)bump((size_t)nb2 * 4);
    int*   sorted   = (int*)bump((size_t)E * 4);
    int*   rowstart = (int*)bump((size_t)(N + 1) * 4);
    float* dinv     = (float*)bump((size_t)N * 4);
    int*   csr_src  = (int*)bump((size_t)E * 4);
    f16*   h        = (f16*)bump((size_t)N * 128 * 2);
    f16*   r1       = (f16*)bump((size_t)N * 128 * 2);
    f16*   h2       = (f16*)bump((size_t)N * 64 * 2);
    f16*   w1t      = (f16*)bump((size_t)128 * 128 * 2);
    f16*   w2t      = (f16*)bump((size_t)64 * 128 * 2);
    float* out      = (float*)d_out;

    // K0: bucket hist + W1/W2 pre-transpose to f16
    degh<<<nblk + 2, 256, 0, stream>>>(dst, histG, W1, W2, w1t, w2t, E, NB, nblk);
    // K2: chunk-local scan of histG + partials
    scanA<<<nb2, 256, 0, stream>>>(histG, bsum, L);
    // K3: place edges bucket-contiguously
    placeK<<<nblk, 256, 0, stream>>>(src, dst, histG, bsum, nb2, sorted, E, NB, nblk);
    // K4: bucket node-sort || MFMA gemm1 (x@W1 -> h f16)
    k4<<<NB + (N + 63) / 64, 256, 0, stream>>>(histG, bsum, nb2, sorted, rowstart, dinv, csr_src,
                                               x, w1t, h, N, E, NB, nblk);
    // K5: gather1 + b1 + relu -> r1~ (f16, dinv-prescaled), 2 nodes/wave
    gather1<<<((N + 1) / 2 + 3) / 4, 256, 0, stream>>>(rowstart, csr_src, dinv, h, b1, r1, N);
    // K6: MFMA gemm2 (r1~@W2 -> h2~ f16)
    gemm2<<<(N + 63) / 64, 256, 0, stream>>>(r1, w2t, h2, N);
    // K7: gather2 + b2 -> out (fp32), 4 nodes/wave
    gather2<<<((N + 3) / 4 + 3) / 4, 256, 0, stream>>>(rowstart, csr_src, dinv, h2, b2, out, N);
}

// Round 8
// 186.898 us; speedup vs baseline: 1.0222x; 1.0222x over previous
//
#include <hip/hip_runtime.h>

typedef _Float16 f16;
typedef f16 f16x2 __attribute__((ext_vector_type(2)));
typedef f16 f16x4 __attribute__((ext_vector_type(4)));
typedef f16 f16x8 __attribute__((ext_vector_type(8)));
typedef float f32x4 __attribute__((ext_vector_type(4)));
typedef int int4a __attribute__((ext_vector_type(4), aligned(4)));  // align-4 dwordx4 load

#define BSH 7    // 128 nodes per bucket
#define BN 128
#define CHUNK 4096  // edges per hist/place block
#define LCAP 4096   // LDS edge cap per bucket (mean ~2046, +45 sigma)
#define NBMAX 512
#define PMAX 512    // padded partial count (nb2 <= 512)

// ============ K0: bucket-hist (blocks 0..nblk-1) + W1/W2 f16 transpose (2 extra blocks) ============
__global__ __launch_bounds__(256) void degh(const int* __restrict__ dst, int* __restrict__ histG,
                                            const float* __restrict__ W1,
                                            const float* __restrict__ W2, f16* __restrict__ w1t,
                                            f16* __restrict__ w2t, int E, int NB, int nblk) {
    const int t = threadIdx.x, blk = blockIdx.x;
    if (blk < nblk) {  // ---- hist role ----
        __shared__ int hist[NBMAX];
        for (int i = t; i < NB; i += 256) hist[i] = 0;
        __syncthreads();
        int lo = blk * CHUNK, hi = min(lo + CHUNK, E);
        for (int i = lo + t; i < hi; i += 256) atomicAdd(&hist[dst[i] >> BSH], 1);
        __syncthreads();
        for (int i = t; i < NB; i += 256) histG[(size_t)i * nblk + blk] = hist[i];
        return;
    }
    if (blk == nblk) {  // ---- W1^T -> f16 : w1t[n][k] = W1[k][n] ----
        for (int idx = t; idx < 128 * 128; idx += 256) {
            int n = idx >> 7, k = idx & 127;
            w1t[idx] = (f16)W1[k * 128 + n];
        }
        return;
    }
    // ---- W2^T -> f16 : w2t[n][k] = W2[k][n], n<64, k<128 ----
    for (int idx = t; idx < 64 * 128; idx += 256) {
        int n = idx >> 7, k = idx & 127;
        w2t[idx] = (f16)W2[k * 64 + n];
    }
}

// ============ K2: per-256-chunk exclusive scan (in place), partials to bsum ============
__global__ __launch_bounds__(256) void scanA(int* __restrict__ a, int* __restrict__ bsum, int L) {
    __shared__ int tmp[256];
    int tid = threadIdx.x;
    int i = blockIdx.x * 256 + tid;
    int v = (i < L) ? a[i] : 0;
    tmp[tid] = v;
    __syncthreads();
    for (int o = 1; o < 256; o <<= 1) {
        int t2 = (tid >= o) ? tmp[tid - o] : 0;
        __syncthreads();
        tmp[tid] += t2;
        __syncthreads();
    }
    if (i < L) a[i] = tmp[tid] - v;  // exclusive within chunk
    if (tid == 255) bsum[blockIdx.x] = tmp[255];
}

// ---- device helper: exclusive-scan bsum[nb2] into LDS excl[PMAX] (256-thread block) ----
__device__ __forceinline__ void scan_partials(const int* __restrict__ bsum, int nb2,
                                              int* excl /*PMAX*/, int* work /*PMAX*/) {
    const int t = threadIdx.x & 255;
    for (int i = t; i < PMAX; i += 256) work[i] = (i < nb2) ? bsum[i] : 0;
    __syncthreads();
    for (int o = 1; o < PMAX; o <<= 1) {
        for (int i = t; i < PMAX; i += 256) excl[i] = work[i] + ((i >= o) ? work[i - o] : 0);
        __syncthreads();
        for (int i = t; i < PMAX; i += 256) work[i] = excl[i];
        __syncthreads();
    }
    for (int i = t; i < PMAX; i += 256) excl[i] = (i == 0) ? 0 : work[i - 1];
    __syncthreads();
}

// ============ K1: place edges (blocks 0..nblk-1) || MFMA GEMM1 (remaining blocks) ============
__global__ __launch_bounds__(256) void k1(const float* __restrict__ x,
                                          const f16* __restrict__ w1t,
                                          const int* __restrict__ src, const int* __restrict__ dst,
                                          const int* __restrict__ histG,
                                          const int* __restrict__ bsum, int nb2,
                                          int* __restrict__ sorted, f16* __restrict__ h, int N,
                                          int E, int NB, int nblk) {
    __shared__ union SM {
        struct {
            f16 aT[64 * 136];
            f16 bT[128 * 136];
        } g;
        struct {
            int excl[PMAX];
            int work[PMAX];
            int ofs[NBMAX];
        } p;
    } sm;
    const int t = threadIdx.x;

    if ((int)blockIdx.x < nblk) {  // ---- place role (bucket-contiguous writes) ----
        const int blk = blockIdx.x;
        scan_partials(bsum, nb2, sm.p.excl, sm.p.work);
        for (int i = t; i < NB; i += 256) {
            int idx = i * nblk + blk;
            sm.p.ofs[i] = histG[idx] + sm.p.excl[idx >> 8];
        }
        __syncthreads();
        int lo = blk * CHUNK, hi = min(lo + CHUNK, E);
        for (int i = lo + t; i < hi; i += 256) {
            int d = dst[i];
            int pos = atomicAdd(&sm.p.ofs[d >> BSH], 1);
            sorted[pos] = (src[i] << BSH) | (d & (BN - 1));
        }
        return;
    }

    // ---- gemm role: h[64 x 128] = x_tile @ W1 (f16) ----
    const int gb = blockIdx.x - nblk;
    const int row0 = gb * 64;
    {  // stage A (fp32 -> fp16), k-contiguous
        int r = t >> 2, s = (t & 3) * 32;
        bool ok = (row0 + r) < N;
        const float* xp = x + (size_t)(row0 + r) * 128 + s;
        f16* dp = &sm.g.aT[r * 136 + s];
#pragma unroll
        for (int c = 0; c < 4; ++c) {
            f16x8 hv;
            if (ok) {
                float4 f0 = *(const float4*)(xp + c * 8);
                float4 f1 = *(const float4*)(xp + c * 8 + 4);
                hv[0] = (f16)f0.x; hv[1] = (f16)f0.y; hv[2] = (f16)f0.z; hv[3] = (f16)f0.w;
                hv[4] = (f16)f1.x; hv[5] = (f16)f1.y; hv[6] = (f16)f1.z; hv[7] = (f16)f1.w;
            } else {
#pragma unroll
                for (int j = 0; j < 8; ++j) hv[j] = (f16)0.f;
            }
            *(f16x8*)(dp + c * 8) = hv;
        }
    }
    for (int idx = t; idx < 128 * 16; idx += 256) {  // stage W1^T (pre-converted, vectorized)
        int n = idx >> 4, c = idx & 15;
        *(f16x8*)&sm.g.bT[n * 136 + c * 8] = *(const f16x8*)&w1t[n * 128 + c * 8];
    }
    __syncthreads();

    const int w = t >> 6, lane = t & 63, m15 = lane & 15, quad = lane >> 4;
    f32x4 acc[8];
#pragma unroll
    for (int c = 0; c < 8; ++c) acc[c] = (f32x4){0.f, 0.f, 0.f, 0.f};
    const f16* ar = &sm.g.aT[(w * 16 + m15) * 136 + quad * 8];
#pragma unroll
    for (int k0 = 0; k0 < 128; k0 += 32) {
        f16x8 a = *(const f16x8*)(ar + k0);
#pragma unroll
        for (int c = 0; c < 8; ++c) {
            f16x8 b = *(const f16x8*)(&sm.g.bT[(c * 16 + m15) * 136 + k0 + quad * 8]);
            acc[c] = __builtin_amdgcn_mfma_f32_16x16x32_f16(a, b, acc[c], 0, 0, 0);
        }
    }
#pragma unroll
    for (int c = 0; c < 8; ++c)
#pragma unroll
        for (int r = 0; r < 4; ++r) {
            int row = row0 + w * 16 + quad * 4 + r;
            if (row < N) h[(size_t)row * 128 + c * 16 + m15] = (f16)acc[c][r];
        }
}

// ============ K4: per-bucket node-sort -> rowstart, dinv, csr_src ============
__global__ __launch_bounds__(256) void bucket_build(const int* __restrict__ histG,
                                                    const int* __restrict__ bsum, int nb2,
                                                    const int* __restrict__ sorted,
                                                    int* __restrict__ rowstart,
                                                    float* __restrict__ dinv,
                                                    int* __restrict__ csr_src, int N, int E,
                                                    int NB, int nblk) {
    __shared__ int ent[LCAP];
    __shared__ int hist[BN];
    __shared__ int lofs[BN];
    __shared__ int excl[PMAX];
    __shared__ int work[PMAX];
    const int b = blockIdx.x, t = threadIdx.x;
    scan_partials(bsum, nb2, excl, work);

    const int i0 = b * nblk;
    const int base = histG[i0] + excl[i0 >> 8];
    const int endb = (b == NB - 1) ? E : (histG[i0 + nblk] + excl[(i0 + nblk) >> 8]);
    int total = min(endb - base, LCAP);
    if (b == 0 && t == 0) rowstart[N] = E;

    for (int i = t; i < total; i += 256) ent[i] = sorted[base + i];
    if (t < BN) hist[t] = 0;
    __syncthreads();
    for (int i = t; i < total; i += 256) atomicAdd(&hist[ent[i] & (BN - 1)], 1);
    __syncthreads();
    if (t < BN) lofs[t] = hist[t];
    __syncthreads();
    for (int o = 1; o < BN; o <<= 1) {
        int v = (t < BN && t >= o) ? lofs[t - o] : 0;
        __syncthreads();
        if (t < BN) lofs[t] += v;
        __syncthreads();
    }
    if (t < BN) {
        int ex = lofs[t] - hist[t];
        int node = (b << BSH) + t;
        if (node < N) {
            rowstart[node] = base + ex;
            dinv[node] = rsqrtf((float)hist[t] + 1.0f);  // +1 self-loop
        }
        lofs[t] = ex;
    }
    __syncthreads();
    for (int i = t; i < total; i += 256) {
        int e = ent[i];
        int pos = atomicAdd(&lofs[e & (BN - 1)], 1);
        csr_src[base + pos] = e >> BSH;
    }
}

// ============ K5: gather1, 2 nodes/wave (32 lanes/node, f16x4), occupancy-pinned ============
__global__ __launch_bounds__(256, 8) void gather1(const int* __restrict__ rowstart,
                                                  const int* __restrict__ csr_src,
                                                  const float* __restrict__ dinv,
                                                  const f16* __restrict__ h,
                                                  const float* __restrict__ b1,
                                                  f16* __restrict__ r1, int N) {
    int wid = (blockIdx.x * 256 + threadIdx.x) >> 6;
    int lane = threadIdx.x & 63;
    int sub = lane >> 5, l32 = lane & 31;
    int node = wid * 2 + sub;
    if (node >= N) return;
    int beg = rowstart[node], end = rowstart[node + 1];
    float dn = dinv[node];
    const f16x4* hv = (const f16x4*)h;  // 32 f16x4 per 128-feat row

    f16x4 sv = hv[(size_t)node * 32 + l32];  // self term
    float a0 = dn * (float)sv[0], a1 = dn * (float)sv[1];
    float a2 = dn * (float)sv[2], a3 = dn * (float)sv[3];
    int i = beg;
    for (; i + 4 <= end; i += 4) {
        int4a s4 = *(const int4a*)(csr_src + i);  // one dwordx4 index load
        float w0 = dinv[s4.x], w1 = dinv[s4.y], w2 = dinv[s4.z], w3 = dinv[s4.w];
        f16x4 v0 = hv[(size_t)s4.x * 32 + l32];
        f16x4 v1 = hv[(size_t)s4.y * 32 + l32];
        f16x4 v2 = hv[(size_t)s4.z * 32 + l32];
        f16x4 v3 = hv[(size_t)s4.w * 32 + l32];
        a0 = fmaf(w0, (float)v0[0], a0); a1 = fmaf(w0, (float)v0[1], a1);
        a2 = fmaf(w0, (float)v0[2], a2); a3 = fmaf(w0, (float)v0[3], a3);
        a0 = fmaf(w1, (float)v1[0], a0); a1 = fmaf(w1, (float)v1[1], a1);
        a2 = fmaf(w1, (float)v1[2], a2); a3 = fmaf(w1, (float)v1[3], a3);
        a0 = fmaf(w2, (float)v2[0], a0); a1 = fmaf(w2, (float)v2[1], a1);
        a2 = fmaf(w2, (float)v2[2], a2); a3 = fmaf(w2, (float)v2[3], a3);
        a0 = fmaf(w3, (float)v3[0], a0); a1 = fmaf(w3, (float)v3[1], a1);
        a2 = fmaf(w3, (float)v3[2], a2); a3 = fmaf(w3, (float)v3[3], a3);
    }
    for (; i < end; ++i) {
        int s = csr_src[i];
        float w = dinv[s];
        f16x4 v = hv[(size_t)s * 32 + l32];
        a0 = fmaf(w, (float)v[0], a0); a1 = fmaf(w, (float)v[1], a1);
        a2 = fmaf(w, (float)v[2], a2); a3 = fmaf(w, (float)v[3], a3);
    }
    float4 bb = ((const float4*)b1)[l32];
    // r1~ = dinv[node] * relu(dinv[node]*sum + b1)  (pre-scaled for layer 2)
    float o0 = dn * fmaxf(fmaf(dn, a0, bb.x), 0.f);
    float o1 = dn * fmaxf(fmaf(dn, a1, bb.y), 0.f);
    float o2 = dn * fmaxf(fmaf(dn, a2, bb.z), 0.f);
    float o3 = dn * fmaxf(fmaf(dn, a3, bb.w), 0.f);
    ((f16x4*)r1)[(size_t)node * 32 + l32] = (f16x4){(f16)o0, (f16)o1, (f16)o2, (f16)o3};
}

// ============ K6: MFMA GEMM2: h2~[N x 64] = r1~ @ W2 (inputs pre-scaled) ============
__global__ __launch_bounds__(256) void gemm2(const f16* __restrict__ r1,
                                             const f16* __restrict__ w2t, f16* __restrict__ h2,
                                             int N) {
    __shared__ f16 aT[64 * 136];
    __shared__ f16 bT[64 * 136];  // W2^T [n][k]
    const int t = threadIdx.x;
    const int row0 = blockIdx.x * 64;
    {
        int r = t >> 2, s = (t & 3) * 32;
        bool ok = (row0 + r) < N;
        const f16* rp = r1 + (size_t)(row0 + r) * 128 + s;
        f16* dp = &aT[r * 136 + s];
#pragma unroll
        for (int c = 0; c < 4; ++c) {
            f16x8 hv;
            if (ok) hv = *(const f16x8*)(rp + c * 8);
            else {
#pragma unroll
                for (int j = 0; j < 8; ++j) hv[j] = (f16)0.f;
            }
            *(f16x8*)(dp + c * 8) = hv;
        }
    }
    for (int idx = t; idx < 64 * 16; idx += 256) {  // stage W2^T (pre-converted, vectorized)
        int n = idx >> 4, c = idx & 15;
        *(f16x8*)&bT[n * 136 + c * 8] = *(const f16x8*)&w2t[n * 128 + c * 8];
    }
    __syncthreads();

    const int w = t >> 6, lane = t & 63, m15 = lane & 15, quad = lane >> 4;
    f32x4 acc[4];
#pragma unroll
    for (int c = 0; c < 4; ++c) acc[c] = (f32x4){0.f, 0.f, 0.f, 0.f};
    const f16* ar = &aT[(w * 16 + m15) * 136 + quad * 8];
#pragma unroll
    for (int k0 = 0; k0 < 128; k0 += 32) {
        f16x8 a = *(const f16x8*)(ar + k0);
#pragma unroll
        for (int c = 0; c < 4; ++c) {
            f16x8 b = *(const f16x8*)(&bT[(c * 16 + m15) * 136 + k0 + quad * 8]);
            acc[c] = __builtin_amdgcn_mfma_f32_16x16x32_f16(a, b, acc[c], 0, 0, 0);
        }
    }
#pragma unroll
    for (int c = 0; c < 4; ++c)
#pragma unroll
        for (int r = 0; r < 4; ++r) {
            int row = row0 + w * 16 + quad * 4 + r;
            if (row < N) h2[(size_t)row * 64 + c * 16 + m15] = (f16)acc[c][r];
        }
}

// ============ K7: gather2, 4 nodes/wave (16 lanes/node, f16x4), occupancy-pinned ============
__global__ __launch_bounds__(256, 8) void gather2(const int* __restrict__ rowstart,
                                                  const int* __restrict__ csr_src,
                                                  const float* __restrict__ dinv,
                                                  const f16* __restrict__ h2,
                                                  const float* __restrict__ b2,
                                                  float* __restrict__ out, int N) {
    int wid = (blockIdx.x * 256 + threadIdx.x) >> 6;
    int lane = threadIdx.x & 63;
    int q = lane >> 4, l16 = lane & 15;
    int node = wid * 4 + q;
    if (node >= N) return;
    int beg = rowstart[node], end = rowstart[node + 1];
    float dn = dinv[node];
    const f16x4* h2v = (const f16x4*)h2;  // 16 f16x4 per 64-feat row

    f16x4 sv = h2v[(size_t)node * 16 + l16];  // self (pre-scaled)
    float a0 = (float)sv[0], a1 = (float)sv[1], a2 = (float)sv[2], a3 = (float)sv[3];
    int i = beg;
    for (; i + 4 <= end; i += 4) {
        int4a s4 = *(const int4a*)(csr_src + i);  // one dwordx4 index load
        f16x4 v0 = h2v[(size_t)s4.x * 16 + l16];
        f16x4 v1 = h2v[(size_t)s4.y * 16 + l16];
        f16x4 v2 = h2v[(size_t)s4.z * 16 + l16];
        f16x4 v3 = h2v[(size_t)s4.w * 16 + l16];
        a0 += (float)v0[0]; a1 += (float)v0[1]; a2 += (float)v0[2]; a3 += (float)v0[3];
        a0 += (float)v1[0]; a1 += (float)v1[1]; a2 += (float)v1[2]; a3 += (float)v1[3];
        a0 += (float)v2[0]; a1 += (float)v2[1]; a2 += (float)v2[2]; a3 += (float)v2[3];
        a0 += (float)v3[0]; a1 += (float)v3[1]; a2 += (float)v3[2]; a3 += (float)v3[3];
    }
    for (; i < end; ++i) {
        int s = csr_src[i];
        f16x4 v = h2v[(size_t)s * 16 + l16];
        a0 += (float)v[0]; a1 += (float)v[1]; a2 += (float)v[2]; a3 += (float)v[3];
    }
    float4 bb = ((const float4*)b2)[l16];
    float4 o;
    o.x = fmaf(dn, a0, bb.x);
    o.y = fmaf(dn, a1, bb.y);
    o.z = fmaf(dn, a2, bb.z);
    o.w = fmaf(dn, a3, bb.w);
    ((float4*)out)[(size_t)node * 16 + l16] = o;
}

extern "C" void kernel_launch(void* const* d_in, const int* in_sizes, int n_in,
                              void* d_out, int out_size, void* d_ws, size_t ws_size,
                              hipStream_t stream) {
    const float* x  = (const float*)d_in[0];
    const int*   ei = (const int*)d_in[1];
    const float* W1 = (const float*)d_in[2];
    const float* b1 = (const float*)d_in[3];
    const float* W2 = (const float*)d_in[4];
    const float* b2 = (const float*)d_in[5];

    const int N = in_sizes[0] / 128;  // 50000
    const int E = in_sizes[1] / 2;    // 800000
    const int* src = ei;
    const int* dst = ei + E;
    const int NB   = (N + BN - 1) >> BSH;      // 391
    const int nblk = (E + CHUNK - 1) / CHUNK;  // 196
    const int L    = NB * nblk;                // 76,636
    const int nb2  = (L + 255) / 256;          // 300 <= PMAX

    char* p = (char*)d_ws;
    auto bump = [&](size_t bytes) {
        char* r = p;
        p += (bytes + 255) & ~(size_t)255;
        return r;
    };
    int*   histG    = (int*)bump((size_t)L * 4);
    int*   bsum     = (int*)bump((size_t)nb2 * 4);
    int*   sorted   = (int*)bump((size_t)E * 4);
    int*   rowstart = (int*)bump((size_t)(N + 1) * 4);
    float* dinv     = (float*)bump((size_t)N * 4);
    int*   csr_src  = (int*)bump((size_t)E * 4);
    f16*   h        = (f16*)bump((size_t)N * 128 * 2);
    f16*   r1       = (f16*)bump((size_t)N * 128 * 2);
    f16*   h2       = (f16*)bump((size_t)N * 64 * 2);
    f16*   w1t      = (f16*)bump((size_t)128 * 128 * 2);
    f16*   w2t      = (f16*)bump((size_t)64 * 128 * 2);
    float* out      = (float*)d_out;

    // K0: bucket hist + W1/W2 pre-transpose to f16
    degh<<<nblk + 2, 256, 0, stream>>>(dst, histG, W1, W2, w1t, w2t, E, NB, nblk);
    // K2: chunk-local scan of histG + partials
    scanA<<<nb2, 256, 0, stream>>>(histG, bsum, L);
    // K1: place (bucket-contiguous) || MFMA gemm1 (x@W1 -> h f16)
    k1<<<nblk + (N + 63) / 64, 256, 0, stream>>>(x, w1t, src, dst, histG, bsum, nb2, sorted, h, N,
                                                 E, NB, nblk);
    // K4: per-bucket node sort -> rowstart, dinv, csr_src
    bucket_build<<<NB, 256, 0, stream>>>(histG, bsum, nb2, sorted, rowstart, dinv, csr_src, N, E,
                                         NB, nblk);
    // K5: gather1 + b1 + relu -> r1~ (f16, dinv-prescaled), 2 nodes/wave
    gather1<<<((N + 1) / 2 + 3) / 4, 256, 0, stream>>>(rowstart, csr_src, dinv, h, b1, r1, N);
    // K6: MFMA gemm2 (r1~@W2 -> h2~ f16)
    gemm2<<<(N + 63) / 64, 256, 0, stream>>>(r1, w2t, h2, N);
    // K7: gather2 + b2 -> out (fp32), 4 nodes/wave
    gather2<<<((N + 3) / 4 + 3) / 4, 256, 0, stream>>>(rowstart, csr_src, dinv, h2, b2, out, N);
}

// Round 9
// 181.245 us; speedup vs baseline: 1.0541x; 1.0312x over previous
//
#include <hip/hip_runtime.h>

typedef _Float16 f16;
typedef f16 f16x2 __attribute__((ext_vector_type(2)));
typedef f16 f16x4 __attribute__((ext_vector_type(4)));
typedef f16 f16x8 __attribute__((ext_vector_type(8)));
typedef float f32x4 __attribute__((ext_vector_type(4)));

#define BSH 7    // 128 nodes per bucket
#define BN 128
#define CHUNK 4096  // edges per hist/place block
#define LCAP 4096   // LDS edge cap per bucket (mean ~2046, +45 sigma)
#define NBMAX 512
#define PMAX 512    // padded partial count (nb2 <= 512)

// ============ K0: bucket-hist (blocks 0..nblk-1) + W1/W2 f16 transpose (2 extra blocks) ============
__global__ __launch_bounds__(256) void degh(const int* __restrict__ dst, int* __restrict__ histG,
                                            const float* __restrict__ W1,
                                            const float* __restrict__ W2, f16* __restrict__ w1t,
                                            f16* __restrict__ w2t, int E, int NB, int nblk) {
    const int t = threadIdx.x, blk = blockIdx.x;
    if (blk < nblk) {  // ---- hist role ----
        __shared__ int hist[NBMAX];
        for (int i = t; i < NB; i += 256) hist[i] = 0;
        __syncthreads();
        int lo = blk * CHUNK, hi = min(lo + CHUNK, E);
        for (int i = lo + t; i < hi; i += 256) atomicAdd(&hist[dst[i] >> BSH], 1);
        __syncthreads();
        for (int i = t; i < NB; i += 256) histG[(size_t)i * nblk + blk] = hist[i];
        return;
    }
    if (blk == nblk) {  // ---- W1^T -> f16 : w1t[n][k] = W1[k][n] ----
        for (int idx = t; idx < 128 * 128; idx += 256) {
            int n = idx >> 7, k = idx & 127;
            w1t[idx] = (f16)W1[k * 128 + n];
        }
        return;
    }
    // ---- W2^T -> f16 : w2t[n][k] = W2[k][n], n<64, k<128 ----
    for (int idx = t; idx < 64 * 128; idx += 256) {
        int n = idx >> 7, k = idx & 127;
        w2t[idx] = (f16)W2[k * 64 + n];
    }
}

// ============ K2: per-256-chunk exclusive scan (in place), partials to bsum ============
__global__ __launch_bounds__(256) void scanA(int* __restrict__ a, int* __restrict__ bsum, int L) {
    __shared__ int tmp[256];
    int tid = threadIdx.x;
    int i = blockIdx.x * 256 + tid;
    int v = (i < L) ? a[i] : 0;
    tmp[tid] = v;
    __syncthreads();
    for (int o = 1; o < 256; o <<= 1) {
        int t2 = (tid >= o) ? tmp[tid - o] : 0;
        __syncthreads();
        tmp[tid] += t2;
        __syncthreads();
    }
    if (i < L) a[i] = tmp[tid] - v;  // exclusive within chunk
    if (tid == 255) bsum[blockIdx.x] = tmp[255];
}

// ---- device helper: exclusive-scan bsum[nb2] into LDS excl[PMAX] (256-thread block) ----
__device__ __forceinline__ void scan_partials(const int* __restrict__ bsum, int nb2,
                                              int* excl /*PMAX*/, int* work /*PMAX*/) {
    const int t = threadIdx.x & 255;
    for (int i = t; i < PMAX; i += 256) work[i] = (i < nb2) ? bsum[i] : 0;
    __syncthreads();
    for (int o = 1; o < PMAX; o <<= 1) {
        for (int i = t; i < PMAX; i += 256) excl[i] = work[i] + ((i >= o) ? work[i - o] : 0);
        __syncthreads();
        for (int i = t; i < PMAX; i += 256) work[i] = excl[i];
        __syncthreads();
    }
    for (int i = t; i < PMAX; i += 256) excl[i] = (i == 0) ? 0 : work[i - 1];
    __syncthreads();
}

// ============ K1: place edges (blocks 0..nblk-1) || MFMA GEMM1 (remaining blocks) ============
__global__ __launch_bounds__(256) void k1(const float* __restrict__ x,
                                          const f16* __restrict__ w1t,
                                          const int* __restrict__ src, const int* __restrict__ dst,
                                          const int* __restrict__ histG,
                                          const int* __restrict__ bsum, int nb2,
                                          int* __restrict__ sorted, f16* __restrict__ h, int N,
                                          int E, int NB, int nblk) {
    __shared__ union SM {
        struct {
            f16 aT[64 * 136];
            f16 bT[128 * 136];
        } g;
        struct {
            int excl[PMAX];
            int work[PMAX];
            int ofs[NBMAX];
        } p;
    } sm;
    const int t = threadIdx.x;

    if ((int)blockIdx.x < nblk) {  // ---- place role (bucket-contiguous writes) ----
        const int blk = blockIdx.x;
        scan_partials(bsum, nb2, sm.p.excl, sm.p.work);
        for (int i = t; i < NB; i += 256) {
            int idx = i * nblk + blk;
            sm.p.ofs[i] = histG[idx] + sm.p.excl[idx >> 8];
        }
        __syncthreads();
        int lo = blk * CHUNK, hi = min(lo + CHUNK, E);
        for (int i = lo + t; i < hi; i += 256) {
            int d = dst[i];
            int pos = atomicAdd(&sm.p.ofs[d >> BSH], 1);
            sorted[pos] = (src[i] << BSH) | (d & (BN - 1));
        }
        return;
    }

    // ---- gemm role: h[64 x 128] = x_tile @ W1 (f16) ----
    const int gb = blockIdx.x - nblk;
    const int row0 = gb * 64;
    {  // stage A (fp32 -> fp16), k-contiguous
        int r = t >> 2, s = (t & 3) * 32;
        bool ok = (row0 + r) < N;
        const float* xp = x + (size_t)(row0 + r) * 128 + s;
        f16* dp = &sm.g.aT[r * 136 + s];
#pragma unroll
        for (int c = 0; c < 4; ++c) {
            f16x8 hv;
            if (ok) {
                float4 f0 = *(const float4*)(xp + c * 8);
                float4 f1 = *(const float4*)(xp + c * 8 + 4);
                hv[0] = (f16)f0.x; hv[1] = (f16)f0.y; hv[2] = (f16)f0.z; hv[3] = (f16)f0.w;
                hv[4] = (f16)f1.x; hv[5] = (f16)f1.y; hv[6] = (f16)f1.z; hv[7] = (f16)f1.w;
            } else {
#pragma unroll
                for (int j = 0; j < 8; ++j) hv[j] = (f16)0.f;
            }
            *(f16x8*)(dp + c * 8) = hv;
        }
    }
    for (int idx = t; idx < 128 * 16; idx += 256) {  // stage W1^T (pre-converted, vectorized)
        int n = idx >> 4, c = idx & 15;
        *(f16x8*)&sm.g.bT[n * 136 + c * 8] = *(const f16x8*)&w1t[n * 128 + c * 8];
    }
    __syncthreads();

    const int w = t >> 6, lane = t & 63, m15 = lane & 15, quad = lane >> 4;
    f32x4 acc[8];
#pragma unroll
    for (int c = 0; c < 8; ++c) acc[c] = (f32x4){0.f, 0.f, 0.f, 0.f};
    const f16* ar = &sm.g.aT[(w * 16 + m15) * 136 + quad * 8];
#pragma unroll
    for (int k0 = 0; k0 < 128; k0 += 32) {
        f16x8 a = *(const f16x8*)(ar + k0);
#pragma unroll
        for (int c = 0; c < 8; ++c) {
            f16x8 b = *(const f16x8*)(&sm.g.bT[(c * 16 + m15) * 136 + k0 + quad * 8]);
            acc[c] = __builtin_amdgcn_mfma_f32_16x16x32_f16(a, b, acc[c], 0, 0, 0);
        }
    }
#pragma unroll
    for (int c = 0; c < 8; ++c)
#pragma unroll
        for (int r = 0; r < 4; ++r) {
            int row = row0 + w * 16 + quad * 4 + r;
            if (row < N) h[(size_t)row * 128 + c * 16 + m15] = (f16)acc[c][r];
        }
}

// ============ K4: per-bucket node-sort -> rowstart, dinv, csr_src ============
__global__ __launch_bounds__(256) void bucket_build(const int* __restrict__ histG,
                                                    const int* __restrict__ bsum, int nb2,
                                                    const int* __restrict__ sorted,
                                                    int* __restrict__ rowstart,
                                                    float* __restrict__ dinv,
                                                    int* __restrict__ csr_src, int N, int E,
                                                    int NB, int nblk) {
    __shared__ int ent[LCAP];
    __shared__ int hist[BN];
    __shared__ int lofs[BN];
    __shared__ int excl[PMAX];
    __shared__ int work[PMAX];
    const int b = blockIdx.x, t = threadIdx.x;
    scan_partials(bsum, nb2, excl, work);

    const int i0 = b * nblk;
    const int base = histG[i0] + excl[i0 >> 8];
    const int endb = (b == NB - 1) ? E : (histG[i0 + nblk] + excl[(i0 + nblk) >> 8]);
    int total = min(endb - base, LCAP);
    if (b == 0 && t == 0) rowstart[N] = E;

    for (int i = t; i < total; i += 256) ent[i] = sorted[base + i];
    if (t < BN) hist[t] = 0;
    __syncthreads();
    for (int i = t; i < total; i += 256) atomicAdd(&hist[ent[i] & (BN - 1)], 1);
    __syncthreads();
    if (t < BN) lofs[t] = hist[t];
    __syncthreads();
    for (int o = 1; o < BN; o <<= 1) {
        int v = (t < BN && t >= o) ? lofs[t - o] : 0;
        __syncthreads();
        if (t < BN) lofs[t] += v;
        __syncthreads();
    }
    if (t < BN) {
        int ex = lofs[t] - hist[t];
        int node = (b << BSH) + t;
        if (node < N) {
            rowstart[node] = base + ex;
            dinv[node] = rsqrtf((float)hist[t] + 1.0f);  // +1 self-loop
        }
        lofs[t] = ex;
    }
    __syncthreads();
    for (int i = t; i < total; i += 256) {
        int e = ent[i];
        int pos = atomicAdd(&lofs[e & (BN - 1)], 1);
        csr_src[base + pos] = e >> BSH;
    }
}

// ============ K5: gather1, 2 nodes/wave (32 lanes/node, f16x4) -> r1~ = dinv*relu(...) ============
__global__ __launch_bounds__(256) void gather1(const int* __restrict__ rowstart,
                                               const int* __restrict__ csr_src,
                                               const float* __restrict__ dinv,
                                               const f16* __restrict__ h,
                                               const float* __restrict__ b1,
                                               f16* __restrict__ r1, int N) {
    int wid = (blockIdx.x * 256 + threadIdx.x) >> 6;
    int lane = threadIdx.x & 63;
    int sub = lane >> 5, l32 = lane & 31;
    int node = wid * 2 + sub;
    if (node >= N) return;
    int beg = rowstart[node], end = rowstart[node + 1];
    float dn = dinv[node];
    const f16x4* hv = (const f16x4*)h;  // 32 f16x4 per 128-feat row

    f16x4 sv = hv[(size_t)node * 32 + l32];  // self term
    float a0 = dn * (float)sv[0], a1 = dn * (float)sv[1];
    float a2 = dn * (float)sv[2], a3 = dn * (float)sv[3];
    int i = beg;
    for (; i + 4 <= end; i += 4) {
        int s0 = csr_src[i], s1 = csr_src[i + 1], s2 = csr_src[i + 2], s3 = csr_src[i + 3];
        float w0 = dinv[s0], w1 = dinv[s1], w2 = dinv[s2], w3 = dinv[s3];
        f16x4 v0 = hv[(size_t)s0 * 32 + l32];
        f16x4 v1 = hv[(size_t)s1 * 32 + l32];
        f16x4 v2 = hv[(size_t)s2 * 32 + l32];
        f16x4 v3 = hv[(size_t)s3 * 32 + l32];
        a0 = fmaf(w0, (float)v0[0], a0); a1 = fmaf(w0, (float)v0[1], a1);
        a2 = fmaf(w0, (float)v0[2], a2); a3 = fmaf(w0, (float)v0[3], a3);
        a0 = fmaf(w1, (float)v1[0], a0); a1 = fmaf(w1, (float)v1[1], a1);
        a2 = fmaf(w1, (float)v1[2], a2); a3 = fmaf(w1, (float)v1[3], a3);
        a0 = fmaf(w2, (float)v2[0], a0); a1 = fmaf(w2, (float)v2[1], a1);
        a2 = fmaf(w2, (float)v2[2], a2); a3 = fmaf(w2, (float)v2[3], a3);
        a0 = fmaf(w3, (float)v3[0], a0); a1 = fmaf(w3, (float)v3[1], a1);
        a2 = fmaf(w3, (float)v3[2], a2); a3 = fmaf(w3, (float)v3[3], a3);
    }
    for (; i < end; ++i) {
        int s = csr_src[i];
        float w = dinv[s];
        f16x4 v = hv[(size_t)s * 32 + l32];
        a0 = fmaf(w, (float)v[0], a0); a1 = fmaf(w, (float)v[1], a1);
        a2 = fmaf(w, (float)v[2], a2); a3 = fmaf(w, (float)v[3], a3);
    }
    float4 bb = ((const float4*)b1)[l32];
    // r1~ = dinv[node] * relu(dinv[node]*sum + b1)  (pre-scaled for layer 2)
    float o0 = dn * fmaxf(fmaf(dn, a0, bb.x), 0.f);
    float o1 = dn * fmaxf(fmaf(dn, a1, bb.y), 0.f);
    float o2 = dn * fmaxf(fmaf(dn, a2, bb.z), 0.f);
    float o3 = dn * fmaxf(fmaf(dn, a3, bb.w), 0.f);
    ((f16x4*)r1)[(size_t)node * 32 + l32] = (f16x4){(f16)o0, (f16)o1, (f16)o2, (f16)o3};
}

// ============ K6: MFMA GEMM2: h2~[N x 64] = r1~ @ W2 (inputs pre-scaled) ============
__global__ __launch_bounds__(256) void gemm2(const f16* __restrict__ r1,
                                             const f16* __restrict__ w2t, f16* __restrict__ h2,
                                             int N) {
    __shared__ f16 aT[64 * 136];
    __shared__ f16 bT[64 * 136];  // W2^T [n][k]
    const int t = threadIdx.x;
    const int row0 = blockIdx.x * 64;
    {
        int r = t >> 2, s = (t & 3) * 32;
        bool ok = (row0 + r) < N;
        const f16* rp = r1 + (size_t)(row0 + r) * 128 + s;
        f16* dp = &aT[r * 136 + s];
#pragma unroll
        for (int c = 0; c < 4; ++c) {
            f16x8 hv;
            if (ok) hv = *(const f16x8*)(rp + c * 8);
            else {
#pragma unroll
                for (int j = 0; j < 8; ++j) hv[j] = (f16)0.f;
            }
            *(f16x8*)(dp + c * 8) = hv;
        }
    }
    for (int idx = t; idx < 64 * 16; idx += 256) {  // stage W2^T (pre-converted, vectorized)
        int n = idx >> 4, c = idx & 15;
        *(f16x8*)&bT[n * 136 + c * 8] = *(const f16x8*)&w2t[n * 128 + c * 8];
    }
    __syncthreads();

    const int w = t >> 6, lane = t & 63, m15 = lane & 15, quad = lane >> 4;
    f32x4 acc[4];
#pragma unroll
    for (int c = 0; c < 4; ++c) acc[c] = (f32x4){0.f, 0.f, 0.f, 0.f};
    const f16* ar = &aT[(w * 16 + m15) * 136 + quad * 8];
#pragma unroll
    for (int k0 = 0; k0 < 128; k0 += 32) {
        f16x8 a = *(const f16x8*)(ar + k0);
#pragma unroll
        for (int c = 0; c < 4; ++c) {
            f16x8 b = *(const f16x8*)(&bT[(c * 16 + m15) * 136 + k0 + quad * 8]);
            acc[c] = __builtin_amdgcn_mfma_f32_16x16x32_f16(a, b, acc[c], 0, 0, 0);
        }
    }
#pragma unroll
    for (int c = 0; c < 4; ++c)
#pragma unroll
        for (int r = 0; r < 4; ++r) {
            int row = row0 + w * 16 + quad * 4 + r;
            if (row < N) h2[(size_t)row * 64 + c * 16 + m15] = (f16)acc[c][r];
        }
}

// ============ K7: gather2, 4 nodes/wave (16 lanes/node, f16x4), pure sum -> fp32 out ============
__global__ __launch_bounds__(256) void gather2(const int* __restrict__ rowstart,
                                               const int* __restrict__ csr_src,
                                               const float* __restrict__ dinv,
                                               const f16* __restrict__ h2,
                                               const float* __restrict__ b2,
                                               float* __restrict__ out, int N) {
    int wid = (blockIdx.x * 256 + threadIdx.x) >> 6;
    int lane = threadIdx.x & 63;
    int q = lane >> 4, l16 = lane & 15;
    int node = wid * 4 + q;
    if (node >= N) return;
    int beg = rowstart[node], end = rowstart[node + 1];
    float dn = dinv[node];
    const f16x4* h2v = (const f16x4*)h2;  // 16 f16x4 per 64-feat row

    f16x4 sv = h2v[(size_t)node * 16 + l16];  // self (pre-scaled)
    float a0 = (float)sv[0], a1 = (float)sv[1], a2 = (float)sv[2], a3 = (float)sv[3];
    int i = beg;
    for (; i + 4 <= end; i += 4) {
        int s0 = csr_src[i], s1 = csr_src[i + 1], s2 = csr_src[i + 2], s3 = csr_src[i + 3];
        f16x4 v0 = h2v[(size_t)s0 * 16 + l16];
        f16x4 v1 = h2v[(size_t)s1 * 16 + l16];
        f16x4 v2 = h2v[(size_t)s2 * 16 + l16];
        f16x4 v3 = h2v[(size_t)s3 * 16 + l16];
        a0 += (float)v0[0]; a1 += (float)v0[1]; a2 += (float)v0[2]; a3 += (float)v0[3];
        a0 += (float)v1[0]; a1 += (float)v1[1]; a2 += (float)v1[2]; a3 += (float)v1[3];
        a0 += (float)v2[0]; a1 += (float)v2[1]; a2 += (float)v2[2]; a3 += (float)v2[3];
        a0 += (float)v3[0]; a1 += (float)v3[1]; a2 += (float)v3[2]; a3 += (float)v3[3];
    }
    for (; i < end; ++i) {
        int s = csr_src[i];
        f16x4 v = h2v[(size_t)s * 16 + l16];
        a0 += (float)v[0]; a1 += (float)v[1]; a2 += (float)v[2]; a3 += (float)v[3];
    }
    float4 bb = ((const float4*)b2)[l16];
    float4 o;
    o.x = fmaf(dn, a0, bb.x);
    o.y = fmaf(dn, a1, bb.y);
    o.z = fmaf(dn, a2, bb.z);
    o.w = fmaf(dn, a3, bb.w);
    ((float4*)out)[(size_t)node * 16 + l16] = o;
}

extern "C" void kernel_launch(void* const* d_in, const int* in_sizes, int n_in,
                              void* d_out, int out_size, void* d_ws, size_t ws_size,
                              hipStream_t stream) {
    const float* x  = (const float*)d_in[0];
    const int*   ei = (const int*)d_in[1];
    const float* W1 = (const float*)d_in[2];
    const float* b1 = (const float*)d_in[3];
    const float* W2 = (const float*)d_in[4];
    const float* b2 = (const float*)d_in[5];

    const int N = in_sizes[0] / 128;  // 50000
    const int E = in_sizes[1] / 2;    // 800000
    const int* src = ei;
    const int* dst = ei + E;
    const int NB   = (N + BN - 1) >> BSH;      // 391
    const int nblk = (E + CHUNK - 1) / CHUNK;  // 196
    const int L    = NB * nblk;                // 76,636
    const int nb2  = (L + 255) / 256;          // 300 <= PMAX

    char* p = (char*)d_ws;
    auto bump = [&](size_t bytes) {
        char* r = p;
        p += (bytes + 255) & ~(size_t)255;
        return r;
    };
    int*   histG    = (int*)bump((size_t)L * 4);
    int*   bsum     = (int*)bump((size_t)nb2 * 4);
    int*   sorted   = (int*)bump((size_t)E * 4);
    int*   rowstart = (int*)bump((size_t)(N + 1) * 4);
    float* dinv     = (float*)bump((size_t)N * 4);
    int*   csr_src  = (int*)bump((size_t)E * 4);
    f16*   h        = (f16*)bump((size_t)N * 128 * 2);
    f16*   r1       = (f16*)bump((size_t)N * 128 * 2);
    f16*   h2       = (f16*)bump((size_t)N * 64 * 2);
    f16*   w1t      = (f16*)bump((size_t)128 * 128 * 2);
    f16*   w2t      = (f16*)bump((size_t)64 * 128 * 2);
    float* out      = (float*)d_out;

    // K0: bucket hist + W1/W2 pre-transpose to f16
    degh<<<nblk + 2, 256, 0, stream>>>(dst, histG, W1, W2, w1t, w2t, E, NB, nblk);
    // K2: chunk-local scan of histG + partials
    scanA<<<nb2, 256, 0, stream>>>(histG, bsum, L);
    // K1: place (bucket-contiguous) || MFMA gemm1 (x@W1 -> h f16)
    k1<<<nblk + (N + 63) / 64, 256, 0, stream>>>(x, w1t, src, dst, histG, bsum, nb2, sorted, h, N,
                                                 E, NB, nblk);
    // K4: per-bucket node sort -> rowstart, dinv, csr_src
    bucket_build<<<NB, 256, 0, stream>>>(histG, bsum, nb2, sorted, rowstart, dinv, csr_src, N, E,
                                         NB, nblk);
    // K5: gather1 + b1 + relu -> r1~ (f16, dinv-prescaled), 2 nodes/wave
    gather1<<<((N + 1) / 2 + 3) / 4, 256, 0, stream>>>(rowstart, csr_src, dinv, h, b1, r1, N);
    // K6: MFMA gemm2 (r1~@W2 -> h2~ f16)
    gemm2<<<(N + 63) / 64, 256, 0, stream>>>(r1, w2t, h2, N);
    // K7: gather2 + b2 -> out (fp32), 4 nodes/wave
    gather2<<<((N + 3) / 4 + 3) / 4, 256, 0, stream>>>(rowstart, csr_src, dinv, h2, b2, out, N);
}